// Round 1
// baseline (441.541 us; speedup 1.0000x reference)
//
#include <hip/hip_runtime.h>

#define H 1024
#define UNITS 1024
#define BATCH 32
#define SEQ 2048
#define M_TOT (BATCH * SEQ)  // 65536

typedef __attribute__((ext_vector_type(8))) short bf16x8;
typedef __attribute__((ext_vector_type(8))) unsigned short u16x8;
typedef __attribute__((ext_vector_type(4))) float f32x4;

__device__ __forceinline__ unsigned short f2bf(float f) {
  union { float f; unsigned u; } x; x.f = f;
  unsigned r = x.u + 0x7FFFu + ((x.u >> 16) & 1u);  // RTN-even
  return (unsigned short)(r >> 16);
}

// ---- W1 [H][U] fp32 -> W1T [U][H] bf16 ----
__global__ void k_transpose_w1(const float* __restrict__ W1, unsigned short* __restrict__ W1T) {
  __shared__ float tile[32][33];
  int bx = blockIdx.x, by = blockIdx.y;
  int tx = threadIdx.x, ty = threadIdx.y;
#pragma unroll
  for (int i = 0; i < 4; ++i)
    tile[ty + i * 8][tx] = W1[(by * 32 + ty + i * 8) * UNITS + bx * 32 + tx];
  __syncthreads();
#pragma unroll
  for (int i = 0; i < 4; ++i)
    W1T[(bx * 32 + ty + i * 8) * H + by * 32 + tx] = f2bf(tile[tx][ty + i * 8]);
}

// ---- projq[b][u] = query[b,:] @ W2[:,u] + b2[u]  (fp32) ----
__global__ void k_projq(const float* __restrict__ query, const float* __restrict__ W2,
                        const float* __restrict__ b2, float* __restrict__ projq) {
  __shared__ float q[H];
  int b = blockIdx.x;
  int u = blockIdx.y * 256 + threadIdx.x;
  for (int i = threadIdx.x; i < H; i += 256) q[i] = query[b * H + i];
  __syncthreads();
  float acc = 0.f;
#pragma unroll 8
  for (int k = 0; k < H; ++k) acc = fmaf(q[k], W2[k * UNITS + u], acc);
  projq[b * UNITS + u] = acc + b2[u];
}

// ---- fused GEMM + tanh + dot(V) -> partial scores ----
#define BM 128
#define BN 128
#define BK 64
#define LDK 72  // +8 bf16 pad: 144B row stride -> 2-way bank aliasing (free)

__global__ __launch_bounds__(256) void k_score(
    const float* __restrict__ values,        // [M_TOT][H] fp32
    const unsigned short* __restrict__ W1T,  // [UNITS][H] bf16
    const float* __restrict__ b1,
    const float* __restrict__ projq,         // [BATCH][UNITS]
    const float* __restrict__ V,
    float* __restrict__ scores)              // [M_TOT], pre-zeroed
{
  __shared__ unsigned short As[BM][LDK];
  __shared__ unsigned short Bs[BN][LDK];

  const int tid = threadIdx.x;
  const int lane = tid & 63;
  const int wave = tid >> 6;
  const int wm = wave >> 1, wn = wave & 1;
  const int li = lane & 15, hi = lane >> 4;

  const int n0 = blockIdx.x * BN;  // x fastest: 8 N-tiles share A rows -> L3 reuse
  const int m0 = blockIdx.y * BM;

  f32x4 acc[4][4] = {};

  for (int k0 = 0; k0 < H; k0 += BK) {
    __syncthreads();
    // stage A: 128x64 fp32 -> bf16 (each thread: 8 x float4)
#pragma unroll
    for (int q = 0; q < 8; ++q) {
      int idx = q * 256 + tid;
      int row = idx >> 4;
      int kc = (idx & 15) << 2;
      float4 v = *reinterpret_cast<const float4*>(&values[(size_t)(m0 + row) * H + k0 + kc]);
      union { unsigned short h[4]; unsigned long long u64; } p;
      p.h[0] = f2bf(v.x); p.h[1] = f2bf(v.y); p.h[2] = f2bf(v.z); p.h[3] = f2bf(v.w);
      *reinterpret_cast<unsigned long long*>(&As[row][kc]) = p.u64;
    }
    // stage B: 128x64 bf16 (each thread: 4 x 16B)
#pragma unroll
    for (int q = 0; q < 4; ++q) {
      int idx = q * 256 + tid;
      int row = idx >> 3;
      int kc = (idx & 7) << 3;
      u16x8 v = *reinterpret_cast<const u16x8*>(&W1T[(size_t)(n0 + row) * H + k0 + kc]);
      *reinterpret_cast<u16x8*>(&Bs[row][kc]) = v;
    }
    __syncthreads();
#pragma unroll
    for (int ks = 0; ks < 2; ++ks) {
      const int kofs = ks * 32 + 8 * hi;
      bf16x8 a[4], bb[4];
#pragma unroll
      for (int i = 0; i < 4; ++i)
        a[i] = *reinterpret_cast<const bf16x8*>(&As[wm * 64 + i * 16 + li][kofs]);
#pragma unroll
      for (int i = 0; i < 4; ++i)
        bb[i] = *reinterpret_cast<const bf16x8*>(&Bs[wn * 64 + i * 16 + li][kofs]);
#pragma unroll
      for (int mi = 0; mi < 4; ++mi)
#pragma unroll
        for (int ni = 0; ni < 4; ++ni)
          acc[mi][ni] = __builtin_amdgcn_mfma_f32_16x16x32_bf16(a[mi], bb[ni], acc[mi][ni], 0, 0, 0);
    }
  }

  // epilogue: score_partial[row] = sum_u tanh(acc + b1[u] + projq[b][u]) * V[u]
  const int b = m0 >> 11;  // BM=128 divides SEQ=2048, so batch is uniform per block
  float bias[4], vv[4];
#pragma unroll
  for (int ni = 0; ni < 4; ++ni) {
    int u = n0 + wn * 64 + ni * 16 + li;
    bias[ni] = b1[u] + projq[b * UNITS + u];
    vv[ni] = V[u];
  }
#pragma unroll
  for (int mi = 0; mi < 4; ++mi) {
#pragma unroll
    for (int r = 0; r < 4; ++r) {
      float s = 0.f;
#pragma unroll
      for (int ni = 0; ni < 4; ++ni) {
        float x = acc[mi][ni][r] + bias[ni];
        float e = __expf(2.f * x);       // tanh(x) = 1 - 2/(e^(2x)+1), saturates correctly
        s += (1.f - 2.f / (e + 1.f)) * vv[ni];
      }
      s += __shfl_xor(s, 1);
      s += __shfl_xor(s, 2);
      s += __shfl_xor(s, 4);
      s += __shfl_xor(s, 8);
      if (li == 0) {
        int row = m0 + wm * 64 + mi * 16 + hi * 4 + r;
        atomicAdd(&scores[row], s);
      }
    }
  }
}

// ---- softmax over S per batch; bv cancels ----
__global__ void k_softmax(const float* __restrict__ scores, float* __restrict__ wts) {
  __shared__ float red[8];
  int b = blockIdx.x;
  int t = threadIdx.x;
  float v[8];
  float mx = -3.4e38f;
#pragma unroll
  for (int i = 0; i < 8; ++i) {
    v[i] = scores[b * SEQ + i * 256 + t];
    mx = fmaxf(mx, v[i]);
  }
#pragma unroll
  for (int o = 1; o < 64; o <<= 1) mx = fmaxf(mx, __shfl_xor(mx, o));
  if ((t & 63) == 0) red[t >> 6] = mx;
  __syncthreads();
  mx = fmaxf(fmaxf(red[0], red[1]), fmaxf(red[2], red[3]));
  float sum = 0.f;
#pragma unroll
  for (int i = 0; i < 8; ++i) { v[i] = __expf(v[i] - mx); sum += v[i]; }
#pragma unroll
  for (int o = 1; o < 64; o <<= 1) sum += __shfl_xor(sum, o);
  if ((t & 63) == 0) red[4 + (t >> 6)] = sum;
  __syncthreads();
  float inv = 1.f / (red[4] + red[5] + red[6] + red[7]);
#pragma unroll
  for (int i = 0; i < 8; ++i) wts[b * SEQ + i * 256 + t] = v[i] * inv;
}

// ---- context[b][h] = sum_s w[b][s] * values[b][s][h] ----
__global__ void k_context(const float* __restrict__ values, const float* __restrict__ wts,
                          float* __restrict__ ctx) {
  int b = blockIdx.x, hc = blockIdx.y, sc = blockIdx.z;
  int h = hc * 256 + threadIdx.x;
  const float* vb = values + (size_t)b * SEQ * H;
  float acc = 0.f;
  int s0 = sc * 128;
#pragma unroll 4
  for (int s = s0; s < s0 + 128; ++s)
    acc = fmaf(wts[b * SEQ + s], vb[(size_t)s * H + h], acc);
  atomicAdd(&ctx[b * H + h], acc);
}

extern "C" void kernel_launch(void* const* d_in, const int* in_sizes, int n_in,
                              void* d_out, int out_size, void* d_ws, size_t ws_size,
                              hipStream_t stream) {
  (void)in_sizes; (void)n_in; (void)out_size; (void)ws_size;
  const float* query  = (const float*)d_in[0];
  const float* values = (const float*)d_in[1];
  const float* W1     = (const float*)d_in[2];
  const float* b1     = (const float*)d_in[3];
  const float* W2     = (const float*)d_in[4];
  const float* b2     = (const float*)d_in[5];
  const float* V      = (const float*)d_in[6];
  // d_in[7] = bv: softmax over scores is invariant to the additive scalar -> unused.

  float* out = (float*)d_out;
  float* ctx = out;             // [32][1024]
  float* wts = out + BATCH * H; // [32][2048]

  char* ws = (char*)d_ws;
  unsigned short* W1T = (unsigned short*)ws;                    // 2 MB
  float* scores = (float*)(ws + (2u << 20));                    // 256 KB
  float* projq  = (float*)(ws + (2u << 20) + (256u << 10));     // 128 KB

  hipMemsetAsync(scores, 0, M_TOT * sizeof(float), stream);
  hipMemsetAsync(ctx, 0, BATCH * H * sizeof(float), stream);

  k_transpose_w1<<<dim3(32, 32), dim3(32, 8), 0, stream>>>(W1, W1T);
  k_projq<<<dim3(32, 4), 256, 0, stream>>>(query, W2, b2, projq);
  k_score<<<dim3(UNITS / BN, M_TOT / BM), 256, 0, stream>>>(values, W1T, b1, projq, V, scores);
  k_softmax<<<BATCH, 256, 0, stream>>>(scores, wts);
  k_context<<<dim3(BATCH, H / 256, 16), 256, 0, stream>>>(values, wts, ctx);
}

// Round 2
// 441.364 us; speedup vs baseline: 1.0004x; 1.0004x over previous
//
#include <hip/hip_runtime.h>

#define H 1024
#define UNITS 1024
#define BATCH 32
#define SEQ 2048
#define M_TOT (BATCH * SEQ)  // 65536

typedef __attribute__((ext_vector_type(8))) short bf16x8;
typedef __attribute__((ext_vector_type(8))) unsigned short u16x8;
typedef __attribute__((ext_vector_type(4))) float f32x4;

__device__ __forceinline__ unsigned short f2bf(float f) {
  union { float f; unsigned u; } x; x.f = f;
  unsigned r = x.u + 0x7FFFu + ((x.u >> 16) & 1u);  // RTN-even
  return (unsigned short)(r >> 16);
}

// ---- W1 [H][U] fp32 -> W1T [U][H] bf16 ----
__global__ void k_transpose_w1(const float* __restrict__ W1, unsigned short* __restrict__ W1T) {
  __shared__ float tile[32][33];
  int bx = blockIdx.x, by = blockIdx.y;
  int tx = threadIdx.x, ty = threadIdx.y;
#pragma unroll
  for (int i = 0; i < 4; ++i)
    tile[ty + i * 8][tx] = W1[(by * 32 + ty + i * 8) * UNITS + bx * 32 + tx];
  __syncthreads();
#pragma unroll
  for (int i = 0; i < 4; ++i)
    W1T[(bx * 32 + ty + i * 8) * H + by * 32 + tx] = f2bf(tile[tx][ty + i * 8]);
}

// ---- projq[b][u] = query[b,:] @ W2[:,u] + b2[u]  (fp32) ----
__global__ void k_projq(const float* __restrict__ query, const float* __restrict__ W2,
                        const float* __restrict__ b2, float* __restrict__ projq) {
  __shared__ float q[H];
  int b = blockIdx.x;
  int u = blockIdx.y * 256 + threadIdx.x;
  for (int i = threadIdx.x; i < H; i += 256) q[i] = query[b * H + i];
  __syncthreads();
  float acc = 0.f;
#pragma unroll 8
  for (int k = 0; k < H; ++k) acc = fmaf(q[k], W2[k * UNITS + u], acc);
  projq[b * UNITS + u] = acc + b2[u];
}

// ---- fused GEMM + tanh + dot(V) -> partial scores ----
#define BM 128
#define BN 128
#define BK 64
#define LDK 72  // +8 bf16 pad: 144B row stride -> 2-way bank aliasing (free)

__global__ __launch_bounds__(256) void k_score(
    const float* __restrict__ values,        // [M_TOT][H] fp32
    const unsigned short* __restrict__ W1T,  // [UNITS][H] bf16
    const float* __restrict__ b1,
    const float* __restrict__ projq,         // [BATCH][UNITS]
    const float* __restrict__ V,
    float* __restrict__ scores)              // [M_TOT], pre-zeroed
{
  __shared__ unsigned short As[BM][LDK];
  __shared__ unsigned short Bs[BN][LDK];

  const int tid = threadIdx.x;
  const int lane = tid & 63;
  const int wave = tid >> 6;
  const int wm = wave >> 1, wn = wave & 1;
  const int li = lane & 15, hi = lane >> 4;

  const int n0 = blockIdx.x * BN;  // x fastest: 8 N-tiles share A rows -> L3 reuse
  const int m0 = blockIdx.y * BM;

  f32x4 acc[4][4] = {};

  for (int k0 = 0; k0 < H; k0 += BK) {
    __syncthreads();
    // stage A: 128x64 fp32 -> bf16 (each thread: 8 x float4)
#pragma unroll
    for (int q = 0; q < 8; ++q) {
      int idx = q * 256 + tid;
      int row = idx >> 4;
      int kc = (idx & 15) << 2;
      float4 v = *reinterpret_cast<const float4*>(&values[(size_t)(m0 + row) * H + k0 + kc]);
      union { unsigned short h[4]; unsigned long long u64; } p;
      p.h[0] = f2bf(v.x); p.h[1] = f2bf(v.y); p.h[2] = f2bf(v.z); p.h[3] = f2bf(v.w);
      *reinterpret_cast<unsigned long long*>(&As[row][kc]) = p.u64;
    }
    // stage B: 128x64 bf16 (each thread: 4 x 16B)
#pragma unroll
    for (int q = 0; q < 4; ++q) {
      int idx = q * 256 + tid;
      int row = idx >> 3;
      int kc = (idx & 7) << 3;
      u16x8 v = *reinterpret_cast<const u16x8*>(&W1T[(size_t)(n0 + row) * H + k0 + kc]);
      *reinterpret_cast<u16x8*>(&Bs[row][kc]) = v;
    }
    __syncthreads();
#pragma unroll
    for (int ks = 0; ks < 2; ++ks) {
      const int kofs = ks * 32 + 8 * hi;
      bf16x8 a[4], bb[4];
#pragma unroll
      for (int i = 0; i < 4; ++i)
        a[i] = *reinterpret_cast<const bf16x8*>(&As[wm * 64 + i * 16 + li][kofs]);
#pragma unroll
      for (int i = 0; i < 4; ++i)
        bb[i] = *reinterpret_cast<const bf16x8*>(&Bs[wn * 64 + i * 16 + li][kofs]);
#pragma unroll
      for (int mi = 0; mi < 4; ++mi)
#pragma unroll
        for (int ni = 0; ni < 4; ++ni)
          acc[mi][ni] = __builtin_amdgcn_mfma_f32_16x16x32_bf16(a[mi], bb[ni], acc[mi][ni], 0, 0, 0);
    }
  }

  // epilogue: score_partial[row] = sum_u tanh(acc + b1[u] + projq[b][u]) * V[u]
  const int b = m0 >> 11;  // BM=128 divides SEQ=2048, so batch is uniform per block
  float bias[4], vv[4];
#pragma unroll
  for (int ni = 0; ni < 4; ++ni) {
    int u = n0 + wn * 64 + ni * 16 + li;
    bias[ni] = b1[u] + projq[b * UNITS + u];
    vv[ni] = V[u];
  }
#pragma unroll
  for (int mi = 0; mi < 4; ++mi) {
#pragma unroll
    for (int r = 0; r < 4; ++r) {
      float s = 0.f;
#pragma unroll
      for (int ni = 0; ni < 4; ++ni) {
        float x = acc[mi][ni][r] + bias[ni];
        float e = __expf(2.f * x);       // tanh(x) = 1 - 2/(e^(2x)+1), saturates correctly
        s += (1.f - 2.f / (e + 1.f)) * vv[ni];
      }
      s += __shfl_xor(s, 1);
      s += __shfl_xor(s, 2);
      s += __shfl_xor(s, 4);
      s += __shfl_xor(s, 8);
      if (li == 0) {
        int row = m0 + wm * 64 + mi * 16 + hi * 4 + r;
        atomicAdd(&scores[row], s);
      }
    }
  }
}

// ---- softmax over S per batch; bv cancels ----
__global__ void k_softmax(const float* __restrict__ scores, float* __restrict__ wts) {
  __shared__ float red[8];
  int b = blockIdx.x;
  int t = threadIdx.x;
  float v[8];
  float mx = -3.4e38f;
#pragma unroll
  for (int i = 0; i < 8; ++i) {
    v[i] = scores[b * SEQ + i * 256 + t];
    mx = fmaxf(mx, v[i]);
  }
#pragma unroll
  for (int o = 1; o < 64; o <<= 1) mx = fmaxf(mx, __shfl_xor(mx, o));
  if ((t & 63) == 0) red[t >> 6] = mx;
  __syncthreads();
  mx = fmaxf(fmaxf(red[0], red[1]), fmaxf(red[2], red[3]));
  float sum = 0.f;
#pragma unroll
  for (int i = 0; i < 8; ++i) { v[i] = __expf(v[i] - mx); sum += v[i]; }
#pragma unroll
  for (int o = 1; o < 64; o <<= 1) sum += __shfl_xor(sum, o);
  if ((t & 63) == 0) red[4 + (t >> 6)] = sum;
  __syncthreads();
  float inv = 1.f / (red[4] + red[5] + red[6] + red[7]);
#pragma unroll
  for (int i = 0; i < 8; ++i) wts[b * SEQ + i * 256 + t] = v[i] * inv;
}

// ---- context[b][h] = sum_s w[b][s] * values[b][s][h] ----
__global__ void k_context(const float* __restrict__ values, const float* __restrict__ wts,
                          float* __restrict__ ctx) {
  int b = blockIdx.x, hc = blockIdx.y, sc = blockIdx.z;
  int h = hc * 256 + threadIdx.x;
  const float* vb = values + (size_t)b * SEQ * H;
  float acc = 0.f;
  int s0 = sc * 128;
#pragma unroll 4
  for (int s = s0; s < s0 + 128; ++s)
    acc = fmaf(wts[b * SEQ + s], vb[(size_t)s * H + h], acc);
  atomicAdd(&ctx[b * H + h], acc);
}

extern "C" void kernel_launch(void* const* d_in, const int* in_sizes, int n_in,
                              void* d_out, int out_size, void* d_ws, size_t ws_size,
                              hipStream_t stream) {
  (void)in_sizes; (void)n_in; (void)out_size; (void)ws_size;
  const float* query  = (const float*)d_in[0];
  const float* values = (const float*)d_in[1];
  const float* W1     = (const float*)d_in[2];
  const float* b1     = (const float*)d_in[3];
  const float* W2     = (const float*)d_in[4];
  const float* b2     = (const float*)d_in[5];
  const float* V      = (const float*)d_in[6];
  // d_in[7] = bv: softmax over scores is invariant to the additive scalar -> unused.

  float* out = (float*)d_out;
  float* ctx = out;             // [32][1024]
  float* wts = out + BATCH * H; // [32][2048]

  char* ws = (char*)d_ws;
  unsigned short* W1T = (unsigned short*)ws;                    // 2 MB
  float* scores = (float*)(ws + (2u << 20));                    // 256 KB
  float* projq  = (float*)(ws + (2u << 20) + (256u << 10));     // 128 KB

  hipMemsetAsync(scores, 0, M_TOT * sizeof(float), stream);
  hipMemsetAsync(ctx, 0, BATCH * H * sizeof(float), stream);

  k_transpose_w1<<<dim3(32, 32), dim3(32, 8), 0, stream>>>(W1, W1T);
  k_projq<<<dim3(32, 4), 256, 0, stream>>>(query, W2, b2, projq);
  k_score<<<dim3(UNITS / BN, M_TOT / BM), 256, 0, stream>>>(values, W1T, b1, projq, V, scores);
  k_softmax<<<BATCH, 256, 0, stream>>>(scores, wts);
  k_context<<<dim3(BATCH, H / 256, 16), 256, 0, stream>>>(values, wts, ctx);
}

// Round 3
// 415.996 us; speedup vs baseline: 1.0614x; 1.0610x over previous
//
#include <hip/hip_runtime.h>

#define H 1024
#define UNITS 1024
#define BATCH 32
#define SEQ 2048
#define M_TOT (BATCH * SEQ)  // 65536

typedef __attribute__((ext_vector_type(8))) short bf16x8;
typedef __attribute__((ext_vector_type(8))) unsigned short u16x8;
typedef __attribute__((ext_vector_type(4))) float f32x4;

__device__ __forceinline__ unsigned short f2bf(float f) {
  union { float f; unsigned u; } x; x.f = f;
  unsigned r = x.u + 0x7FFFu + ((x.u >> 16) & 1u);  // RTN-even
  return (unsigned short)(r >> 16);
}
__device__ __forceinline__ float bf2f(unsigned short h) {
  union { unsigned u; float f; } x; x.u = (unsigned)h << 16;
  return x.f;
}

// async global->LDS, 16B per lane; LDS dest = wave-uniform base + lane*16
__device__ __forceinline__ void gll16(const unsigned short* g, unsigned short* l) {
  __builtin_amdgcn_global_load_lds(
      (const __attribute__((address_space(1))) void*)g,
      (__attribute__((address_space(3))) void*)l, 16, 0, 0);
}

// ---- values fp32 -> bf16 (one-shot, BW-bound) ----
__global__ void k_cast(const float* __restrict__ in, unsigned short* __restrict__ out) {
  size_t i = ((size_t)blockIdx.x * 256 + threadIdx.x) * 8;
  float4 v0 = *reinterpret_cast<const float4*>(in + i);
  float4 v1 = *reinterpret_cast<const float4*>(in + i + 4);
  union { unsigned short h[8]; u16x8 v; } p;
  p.h[0] = f2bf(v0.x); p.h[1] = f2bf(v0.y); p.h[2] = f2bf(v0.z); p.h[3] = f2bf(v0.w);
  p.h[4] = f2bf(v1.x); p.h[5] = f2bf(v1.y); p.h[6] = f2bf(v1.z); p.h[7] = f2bf(v1.w);
  *reinterpret_cast<u16x8*>(out + i) = p.v;
}

// ---- W1 [H][U] fp32 -> W1T [U][H] bf16 ----
__global__ void k_transpose_w1(const float* __restrict__ W1, unsigned short* __restrict__ W1T) {
  __shared__ float tile[32][33];
  int bx = blockIdx.x, by = blockIdx.y;
  int tx = threadIdx.x, ty = threadIdx.y;
#pragma unroll
  for (int i = 0; i < 4; ++i)
    tile[ty + i * 8][tx] = W1[(by * 32 + ty + i * 8) * UNITS + bx * 32 + tx];
  __syncthreads();
#pragma unroll
  for (int i = 0; i < 4; ++i)
    W1T[(bx * 32 + ty + i * 8) * H + by * 32 + tx] = f2bf(tile[tx][ty + i * 8]);
}

// ---- projq[b][u] = query[b,:] @ W2[:,u] + b2[u]  (fp32) ----
__global__ void k_projq(const float* __restrict__ query, const float* __restrict__ W2,
                        const float* __restrict__ b2, float* __restrict__ projq) {
  __shared__ float q[H];
  int b = blockIdx.x;
  int u = blockIdx.y * 256 + threadIdx.x;
  for (int i = threadIdx.x; i < H; i += 256) q[i] = query[b * H + i];
  __syncthreads();
  float acc = 0.f;
#pragma unroll 8
  for (int k = 0; k < H; ++k) acc = fmaf(q[k], W2[k * UNITS + u], acc);
  projq[b * UNITS + u] = acc + b2[u];
}

// ================= fused GEMM + tanh + dot(V) -> partial scores ==============
#define BM 128
#define BN 128
#define BK 64

// m97 structure: bf16 A/B, global_load_lds width-16 staging, linear LDS,
// 2-barrier K-loop. XCD-bijective swizzle: the 8 N-tiles of one M-tile all
// have linear id === xcd (mod 8) and are consecutive in that XCD's queue,
// so the 256 KB bf16 A-panel stays in the XCD's 4 MB L2.
__global__ __launch_bounds__(256) void k_score2(
    const unsigned short* __restrict__ Vb,   // values bf16 [M_TOT][H]
    const unsigned short* __restrict__ W1T,  // [UNITS][H] bf16
    const float* __restrict__ b1,
    const float* __restrict__ projq,         // [BATCH][UNITS]
    const float* __restrict__ V,
    float* __restrict__ scores)              // [M_TOT], pre-zeroed
{
  __shared__ unsigned short As[BM][BK];  // 16 KB, linear (global_load_lds dest)
  __shared__ unsigned short Bs[BN][BK];  // 16 KB

  const int tid = threadIdx.x;
  const int lane = tid & 63;
  const int wave = tid >> 6;
  const int wm = wave >> 1, wn = wave & 1;
  const int li = lane & 15, hi = lane >> 4;

  // swizzle: g = xcd + 8*(n_t + 8*mg); m_t = xcd + 8*mg
  const int g = blockIdx.x;
  const int xcd = g & 7;
  const int local = g >> 3;
  const int n_t = local & 7;
  const int m_t = xcd + ((local >> 3) << 3);
  const int m0 = m_t * BM;
  const int n0 = n_t * BN;

  const int lrow = lane >> 3;          // 0..7 row within 8-row chunk
  const int lcol = (lane & 7) << 3;    // 0..56 halves

  f32x4 acc[4][4] = {};

  for (int k0 = 0; k0 < H; k0 += BK) {
    __syncthreads();
    // stage A,B: 4 chunks each per wave, 8 rows x 64 halves (1 KB) per chunk
#pragma unroll
    for (int q = 0; q < 4; ++q) {
      int c = wave * 4 + q;
      int r = c * 8 + lrow;
      gll16(&Vb[(size_t)(m0 + r) * H + k0 + lcol], &As[c * 8][0]);
      gll16(&W1T[(size_t)(n0 + r) * H + k0 + lcol], &Bs[c * 8][0]);
    }
    __syncthreads();  // drains vmcnt(0) -> LDS ready
#pragma unroll
    for (int ks = 0; ks < 2; ++ks) {
      const int kofs = ks * 32 + 8 * hi;
      bf16x8 a[4], bb[4];
#pragma unroll
      for (int i = 0; i < 4; ++i)
        a[i] = *reinterpret_cast<const bf16x8*>(&As[wm * 64 + i * 16 + li][kofs]);
#pragma unroll
      for (int i = 0; i < 4; ++i)
        bb[i] = *reinterpret_cast<const bf16x8*>(&Bs[wn * 64 + i * 16 + li][kofs]);
#pragma unroll
      for (int mi = 0; mi < 4; ++mi)
#pragma unroll
        for (int ni = 0; ni < 4; ++ni)
          acc[mi][ni] = __builtin_amdgcn_mfma_f32_16x16x32_bf16(a[mi], bb[ni], acc[mi][ni], 0, 0, 0);
    }
  }

  // epilogue: partial score[row] = sum_u tanh(acc + b1[u] + projq[b][u]) * V[u]
  const int b = m0 >> 11;  // BM divides SEQ, batch uniform per block
  float bias[4], vv[4];
#pragma unroll
  for (int ni = 0; ni < 4; ++ni) {
    int u = n0 + wn * 64 + ni * 16 + li;
    bias[ni] = b1[u] + projq[b * UNITS + u];
    vv[ni] = V[u];
  }
#pragma unroll
  for (int mi = 0; mi < 4; ++mi) {
#pragma unroll
    for (int r = 0; r < 4; ++r) {
      float s = 0.f;
#pragma unroll
      for (int ni = 0; ni < 4; ++ni) {
        float x = acc[mi][ni][r] + bias[ni];
        float e = __expf(2.f * x);       // tanh(x) = 1 - 2/(e^(2x)+1)
        s += (1.f - 2.f / (e + 1.f)) * vv[ni];
      }
      s += __shfl_xor(s, 1);
      s += __shfl_xor(s, 2);
      s += __shfl_xor(s, 4);
      s += __shfl_xor(s, 8);
      if (li == 0) {
        int row = m0 + wm * 64 + mi * 16 + hi * 4 + r;
        atomicAdd(&scores[row], s);
      }
    }
  }
}

// ---- fallback fp32-A score kernel (R1 version, used only if ws too small) ----
#define LDK 72
__global__ __launch_bounds__(256) void k_score_f32(
    const float* __restrict__ values, const unsigned short* __restrict__ W1T,
    const float* __restrict__ b1, const float* __restrict__ projq,
    const float* __restrict__ V, float* __restrict__ scores)
{
  __shared__ unsigned short As[BM][LDK];
  __shared__ unsigned short Bs[BN][LDK];
  const int tid = threadIdx.x;
  const int lane = tid & 63;
  const int wave = tid >> 6;
  const int wm = wave >> 1, wn = wave & 1;
  const int li = lane & 15, hi = lane >> 4;
  const int n0 = blockIdx.x * BN;
  const int m0 = blockIdx.y * BM;
  f32x4 acc[4][4] = {};
  for (int k0 = 0; k0 < H; k0 += BK) {
    __syncthreads();
#pragma unroll
    for (int q = 0; q < 8; ++q) {
      int idx = q * 256 + tid;
      int row = idx >> 4;
      int kc = (idx & 15) << 2;
      float4 v = *reinterpret_cast<const float4*>(&values[(size_t)(m0 + row) * H + k0 + kc]);
      union { unsigned short h[4]; unsigned long long u64; } p;
      p.h[0] = f2bf(v.x); p.h[1] = f2bf(v.y); p.h[2] = f2bf(v.z); p.h[3] = f2bf(v.w);
      *reinterpret_cast<unsigned long long*>(&As[row][kc]) = p.u64;
    }
#pragma unroll
    for (int q = 0; q < 4; ++q) {
      int idx = q * 256 + tid;
      int row = idx >> 3;
      int kc = (idx & 7) << 3;
      *reinterpret_cast<u16x8*>(&Bs[row][kc]) =
          *reinterpret_cast<const u16x8*>(&W1T[(size_t)(n0 + row) * H + k0 + kc]);
    }
    __syncthreads();
#pragma unroll
    for (int ks = 0; ks < 2; ++ks) {
      const int kofs = ks * 32 + 8 * hi;
      bf16x8 a[4], bb[4];
#pragma unroll
      for (int i = 0; i < 4; ++i)
        a[i] = *reinterpret_cast<const bf16x8*>(&As[wm * 64 + i * 16 + li][kofs]);
#pragma unroll
      for (int i = 0; i < 4; ++i)
        bb[i] = *reinterpret_cast<const bf16x8*>(&Bs[wn * 64 + i * 16 + li][kofs]);
#pragma unroll
      for (int mi = 0; mi < 4; ++mi)
#pragma unroll
        for (int ni = 0; ni < 4; ++ni)
          acc[mi][ni] = __builtin_amdgcn_mfma_f32_16x16x32_bf16(a[mi], bb[ni], acc[mi][ni], 0, 0, 0);
    }
  }
  const int b = m0 >> 11;
  float bias[4], vv[4];
#pragma unroll
  for (int ni = 0; ni < 4; ++ni) {
    int u = n0 + wn * 64 + ni * 16 + li;
    bias[ni] = b1[u] + projq[b * UNITS + u];
    vv[ni] = V[u];
  }
#pragma unroll
  for (int mi = 0; mi < 4; ++mi) {
#pragma unroll
    for (int r = 0; r < 4; ++r) {
      float s = 0.f;
#pragma unroll
      for (int ni = 0; ni < 4; ++ni) {
        float x = acc[mi][ni][r] + bias[ni];
        float e = __expf(2.f * x);
        s += (1.f - 2.f / (e + 1.f)) * vv[ni];
      }
      s += __shfl_xor(s, 1);
      s += __shfl_xor(s, 2);
      s += __shfl_xor(s, 4);
      s += __shfl_xor(s, 8);
      if (li == 0) atomicAdd(&scores[m0 + wm * 64 + mi * 16 + hi * 4 + r], s);
    }
  }
}

// ---- softmax over S per batch; bv cancels ----
__global__ void k_softmax(const float* __restrict__ scores, float* __restrict__ wts) {
  __shared__ float red[8];
  int b = blockIdx.x;
  int t = threadIdx.x;
  float v[8];
  float mx = -3.4e38f;
#pragma unroll
  for (int i = 0; i < 8; ++i) {
    v[i] = scores[b * SEQ + i * 256 + t];
    mx = fmaxf(mx, v[i]);
  }
#pragma unroll
  for (int o = 1; o < 64; o <<= 1) mx = fmaxf(mx, __shfl_xor(mx, o));
  if ((t & 63) == 0) red[t >> 6] = mx;
  __syncthreads();
  mx = fmaxf(fmaxf(red[0], red[1]), fmaxf(red[2], red[3]));
  float sum = 0.f;
#pragma unroll
  for (int i = 0; i < 8; ++i) { v[i] = __expf(v[i] - mx); sum += v[i]; }
#pragma unroll
  for (int o = 1; o < 64; o <<= 1) sum += __shfl_xor(sum, o);
  if ((t & 63) == 0) red[4 + (t >> 6)] = sum;
  __syncthreads();
  float inv = 1.f / (red[4] + red[5] + red[6] + red[7]);
#pragma unroll
  for (int i = 0; i < 8; ++i) wts[b * SEQ + i * 256 + t] = v[i] * inv;
}

// ---- context from bf16 values: ctx[b][h] = sum_s w[b][s]*v[b][s][h] ----
__global__ void k_context_bf(const unsigned short* __restrict__ Vb,
                             const float* __restrict__ wts, float* __restrict__ ctx) {
  int b = blockIdx.x, sc = blockIdx.y;
  int h4 = threadIdx.x * 4;
  const unsigned short* vb = Vb + (size_t)b * SEQ * H;
  float a0 = 0, a1 = 0, a2 = 0, a3 = 0;
  int s0 = sc * 128;
#pragma unroll 4
  for (int s = s0; s < s0 + 128; ++s) {
    float w = wts[b * SEQ + s];
    ushort4 v = *reinterpret_cast<const ushort4*>(&vb[(size_t)s * H + h4]);
    a0 = fmaf(w, bf2f(v.x), a0);
    a1 = fmaf(w, bf2f(v.y), a1);
    a2 = fmaf(w, bf2f(v.z), a2);
    a3 = fmaf(w, bf2f(v.w), a3);
  }
  atomicAdd(&ctx[b * H + h4 + 0], a0);
  atomicAdd(&ctx[b * H + h4 + 1], a1);
  atomicAdd(&ctx[b * H + h4 + 2], a2);
  atomicAdd(&ctx[b * H + h4 + 3], a3);
}

// ---- fp32 context (fallback path) ----
__global__ void k_context(const float* __restrict__ values, const float* __restrict__ wts,
                          float* __restrict__ ctx) {
  int b = blockIdx.x, hc = blockIdx.y, sc = blockIdx.z;
  int h = hc * 256 + threadIdx.x;
  const float* vb = values + (size_t)b * SEQ * H;
  float acc = 0.f;
  int s0 = sc * 128;
#pragma unroll 4
  for (int s = s0; s < s0 + 128; ++s)
    acc = fmaf(wts[b * SEQ + s], vb[(size_t)s * H + h], acc);
  atomicAdd(&ctx[b * H + h], acc);
}

extern "C" void kernel_launch(void* const* d_in, const int* in_sizes, int n_in,
                              void* d_out, int out_size, void* d_ws, size_t ws_size,
                              hipStream_t stream) {
  (void)in_sizes; (void)n_in; (void)out_size;
  const float* query  = (const float*)d_in[0];
  const float* values = (const float*)d_in[1];
  const float* W1     = (const float*)d_in[2];
  const float* b1     = (const float*)d_in[3];
  const float* W2     = (const float*)d_in[4];
  const float* b2     = (const float*)d_in[5];
  const float* V      = (const float*)d_in[6];
  // d_in[7] = bv: cancels in softmax -> unused.

  float* out = (float*)d_out;
  float* ctx = out;             // [32][1024]
  float* wts = out + BATCH * H; // [32][2048]

  const size_t vb_bytes = (size_t)M_TOT * H * 2;  // 128 MB
  const size_t need = vb_bytes + (2u << 20) + (256u << 10) + (128u << 10);

  if (ws_size >= need) {
    char* ws = (char*)d_ws;
    unsigned short* Vb  = (unsigned short*)ws;
    unsigned short* W1T = (unsigned short*)(ws + vb_bytes);
    float* scores = (float*)(ws + vb_bytes + (2u << 20));
    float* projq  = (float*)(ws + vb_bytes + (2u << 20) + (256u << 10));

    hipMemsetAsync(scores, 0, M_TOT * sizeof(float), stream);
    hipMemsetAsync(ctx, 0, BATCH * H * sizeof(float), stream);

    k_cast<<<(M_TOT * H / 8) / 256, 256, 0, stream>>>(values, Vb);
    k_transpose_w1<<<dim3(32, 32), dim3(32, 8), 0, stream>>>(W1, W1T);
    k_projq<<<dim3(32, 4), 256, 0, stream>>>(query, W2, b2, projq);
    k_score2<<<(M_TOT / BM) * (UNITS / BN), 256, 0, stream>>>(Vb, W1T, b1, projq, V, scores);
    k_softmax<<<BATCH, 256, 0, stream>>>(scores, wts);
    k_context_bf<<<dim3(BATCH, 16), 256, 0, stream>>>(Vb, wts, ctx);
  } else {
    char* ws = (char*)d_ws;
    unsigned short* W1T = (unsigned short*)ws;
    float* scores = (float*)(ws + (2u << 20));
    float* projq  = (float*)(ws + (2u << 20) + (256u << 10));

    hipMemsetAsync(scores, 0, M_TOT * sizeof(float), stream);
    hipMemsetAsync(ctx, 0, BATCH * H * sizeof(float), stream);

    k_transpose_w1<<<dim3(32, 32), dim3(32, 8), 0, stream>>>(W1, W1T);
    k_projq<<<dim3(32, 4), 256, 0, stream>>>(query, W2, b2, projq);
    k_score_f32<<<dim3(UNITS / BN, M_TOT / BM), 256, 0, stream>>>(values, W1T, b1, projq, V, scores);
    k_softmax<<<BATCH, 256, 0, stream>>>(scores, wts);
    k_context<<<dim3(BATCH, H / 256, 16), 256, 0, stream>>>(values, wts, ctx);
  }
}

// Round 4
// 356.159 us; speedup vs baseline: 1.2397x; 1.1680x over previous
//
#include <hip/hip_runtime.h>

#define H 1024
#define UNITS 1024
#define BATCH 32
#define SEQ 2048
#define M_TOT (BATCH * SEQ)  // 65536

typedef __attribute__((ext_vector_type(8))) short bf16x8;
typedef __attribute__((ext_vector_type(8))) unsigned short u16x8;
typedef __attribute__((ext_vector_type(4))) float f32x4;

__device__ __forceinline__ unsigned short f2bf(float f) {
  union { float f; unsigned u; } x; x.f = f;
  unsigned r = x.u + 0x7FFFu + ((x.u >> 16) & 1u);  // RTN-even
  return (unsigned short)(r >> 16);
}
__device__ __forceinline__ float bf2f(unsigned short h) {
  union { unsigned u; float f; } x; x.u = (unsigned)h << 16;
  return x.f;
}

// async global->LDS, 16B per lane; LDS dest = wave-uniform base + lane*16
__device__ __forceinline__ void gll16(const unsigned short* g, unsigned short* l) {
  __builtin_amdgcn_global_load_lds(
      (const __attribute__((address_space(1))) void*)g,
      (__attribute__((address_space(3))) void*)l, 16, 0, 0);
}

// ---- values fp32 -> bf16 (one-shot, BW-bound) ----
__global__ void k_cast(const float* __restrict__ in, unsigned short* __restrict__ out) {
  size_t i = ((size_t)blockIdx.x * 256 + threadIdx.x) * 8;
  float4 v0 = *reinterpret_cast<const float4*>(in + i);
  float4 v1 = *reinterpret_cast<const float4*>(in + i + 4);
  union { unsigned short h[8]; u16x8 v; } p;
  p.h[0] = f2bf(v0.x); p.h[1] = f2bf(v0.y); p.h[2] = f2bf(v0.z); p.h[3] = f2bf(v0.w);
  p.h[4] = f2bf(v1.x); p.h[5] = f2bf(v1.y); p.h[6] = f2bf(v1.z); p.h[7] = f2bf(v1.w);
  *reinterpret_cast<u16x8*>(out + i) = p.v;
}

// ---- W1 [H][U] fp32 -> W1T [U][H] bf16 ----
__global__ void k_transpose_w1(const float* __restrict__ W1, unsigned short* __restrict__ W1T) {
  __shared__ float tile[32][33];
  int bx = blockIdx.x, by = blockIdx.y;
  int tx = threadIdx.x, ty = threadIdx.y;
#pragma unroll
  for (int i = 0; i < 4; ++i)
    tile[ty + i * 8][tx] = W1[(by * 32 + ty + i * 8) * UNITS + bx * 32 + tx];
  __syncthreads();
#pragma unroll
  for (int i = 0; i < 4; ++i)
    W1T[(bx * 32 + ty + i * 8) * H + by * 32 + tx] = f2bf(tile[tx][ty + i * 8]);
}

// ---- projq[b][u] = query[b,:] @ W2[:,u] + b2[u]  (fp32) ----
__global__ void k_projq(const float* __restrict__ query, const float* __restrict__ W2,
                        const float* __restrict__ b2, float* __restrict__ projq) {
  __shared__ float q[H];
  int b = blockIdx.x;
  int u = blockIdx.y * 256 + threadIdx.x;
  for (int i = threadIdx.x; i < H; i += 256) q[i] = query[b * H + i];
  __syncthreads();
  float acc = 0.f;
#pragma unroll 8
  for (int k = 0; k < H; ++k) acc = fmaf(q[k], W2[k * UNITS + u], acc);
  projq[b * UNITS + u] = acc + b2[u];
}

// ================= fused GEMM + tanh + dot(V) -> partial scores ==============
#define BM 128
#define BN 128
#define BK 64

// Double-buffered (T3 minimum pipeline) + both-sides XOR swizzle (rule 21):
//   store: lane l of a chunk fetches global slot (l&7)^(l>>3) -> LDS linear
//   read:  slot = (ks*4+hi) ^ (row&7)  (same involution, bijective per row)
// After swizzle a wave's 64 b128-lanes spread uniformly 8-per-slot = the
// ds_read_b128 floor. XCD-bijective block swizzle keeps the A-panel L2-hot.
__global__ __launch_bounds__(256) void k_score2(
    const unsigned short* __restrict__ Vb,   // values bf16 [M_TOT][H]
    const unsigned short* __restrict__ W1T,  // [UNITS][H] bf16
    const float* __restrict__ b1,
    const float* __restrict__ projq,         // [BATCH][UNITS]
    const float* __restrict__ V,
    float* __restrict__ scores)              // [M_TOT], pre-zeroed
{
  __shared__ unsigned short As[2][BM][BK];  // 2 x 16 KB
  __shared__ unsigned short Bs[2][BN][BK];  // 2 x 16 KB

  const int tid = threadIdx.x;
  const int lane = tid & 63;
  const int wave = tid >> 6;
  const int wm = wave >> 1, wn = wave & 1;
  const int li = lane & 15, hi = lane >> 4;

  // swizzle: g = xcd + 8*(n_t + 8*mg); m_t = xcd + 8*mg  (all 8 n_t on one XCD)
  const int g = blockIdx.x;
  const int xcd = g & 7;
  const int local = g >> 3;
  const int n_t = local & 7;
  const int m_t = xcd + ((local >> 3) << 3);
  const int m0 = m_t * BM;
  const int n0 = n_t * BN;

  const int lrow = lane >> 3;                              // row within 8-row chunk
  const int lcolsw = (((lane & 7) ^ (lane >> 3)) << 3);    // pre-swizzled source col (halves)

  f32x4 acc[4][4] = {};

  // stage one 64-wide K-slice of A and B into buffer `buf`
  auto STAGE = [&](int buf, int k0) {
#pragma unroll
    for (int q = 0; q < 4; ++q) {
      int c = wave * 4 + q;
      int r = c * 8 + lrow;
      gll16(&Vb[(size_t)(m0 + r) * H + k0 + lcolsw], &As[buf][c * 8][0]);
      gll16(&W1T[(size_t)(n0 + r) * H + k0 + lcolsw], &Bs[buf][c * 8][0]);
    }
  };

  auto COMPUTE = [&](int buf) {
#pragma unroll
    for (int ks = 0; ks < 2; ++ks) {
      bf16x8 a[4], bb[4];
#pragma unroll
      for (int i = 0; i < 4; ++i) {
        int r = wm * 64 + i * 16 + li;
        a[i] = *reinterpret_cast<const bf16x8*>(
            &As[buf][r][(((ks << 2) + hi) ^ (li & 7)) << 3]);
      }
#pragma unroll
      for (int i = 0; i < 4; ++i) {
        int r = wn * 64 + i * 16 + li;
        bb[i] = *reinterpret_cast<const bf16x8*>(
            &Bs[buf][r][(((ks << 2) + hi) ^ (li & 7)) << 3]);
      }
      __builtin_amdgcn_s_setprio(1);
#pragma unroll
      for (int mi = 0; mi < 4; ++mi)
#pragma unroll
        for (int ni = 0; ni < 4; ++ni)
          acc[mi][ni] = __builtin_amdgcn_mfma_f32_16x16x32_bf16(a[mi], bb[ni], acc[mi][ni], 0, 0, 0);
      __builtin_amdgcn_s_setprio(0);
    }
  };

  STAGE(0, 0);
  __syncthreads();  // drains vmcnt(0) -> buf0 ready
#pragma unroll
  for (int t = 0; t < 15; ++t) {
    const int cur = t & 1;
    STAGE(cur ^ 1, (t + 1) << 6);  // issue next-slice loads (async, overlaps compute)
    COMPUTE(cur);
    __syncthreads();               // drains vmcnt -> next buffer ready; LDS reads done
  }
  COMPUTE(1);

  // epilogue: partial score[row] = sum_u tanh(acc + b1[u] + projq[b][u]) * V[u]
  const int b = m0 >> 11;  // BM divides SEQ, batch uniform per block
  float bias[4], vv[4];
#pragma unroll
  for (int ni = 0; ni < 4; ++ni) {
    int u = n0 + wn * 64 + ni * 16 + li;
    bias[ni] = b1[u] + projq[b * UNITS + u];
    vv[ni] = V[u];
  }
#pragma unroll
  for (int mi = 0; mi < 4; ++mi) {
#pragma unroll
    for (int r = 0; r < 4; ++r) {
      float s = 0.f;
#pragma unroll
      for (int ni = 0; ni < 4; ++ni) {
        float x = acc[mi][ni][r] + bias[ni];
        float e = __expf(2.f * x);       // tanh(x) = 1 - 2/(e^(2x)+1)
        s += (1.f - 2.f / (e + 1.f)) * vv[ni];
      }
      s += __shfl_xor(s, 1);
      s += __shfl_xor(s, 2);
      s += __shfl_xor(s, 4);
      s += __shfl_xor(s, 8);
      if (li == 0) {
        int row = m0 + wm * 64 + mi * 16 + hi * 4 + r;
        atomicAdd(&scores[row], s);
      }
    }
  }
}

// ---- fallback fp32-A score kernel (used only if ws too small) ----
#define LDK 72
__global__ __launch_bounds__(256) void k_score_f32(
    const float* __restrict__ values, const unsigned short* __restrict__ W1T,
    const float* __restrict__ b1, const float* __restrict__ projq,
    const float* __restrict__ V, float* __restrict__ scores)
{
  __shared__ unsigned short As[BM][LDK];
  __shared__ unsigned short Bs[BN][LDK];
  const int tid = threadIdx.x;
  const int lane = tid & 63;
  const int wave = tid >> 6;
  const int wm = wave >> 1, wn = wave & 1;
  const int li = lane & 15, hi = lane >> 4;
  const int n0 = blockIdx.x * BN;
  const int m0 = blockIdx.y * BM;
  f32x4 acc[4][4] = {};
  for (int k0 = 0; k0 < H; k0 += BK) {
    __syncthreads();
#pragma unroll
    for (int q = 0; q < 8; ++q) {
      int idx = q * 256 + tid;
      int row = idx >> 4;
      int kc = (idx & 15) << 2;
      float4 v = *reinterpret_cast<const float4*>(&values[(size_t)(m0 + row) * H + k0 + kc]);
      union { unsigned short h[4]; unsigned long long u64; } p;
      p.h[0] = f2bf(v.x); p.h[1] = f2bf(v.y); p.h[2] = f2bf(v.z); p.h[3] = f2bf(v.w);
      *reinterpret_cast<unsigned long long*>(&As[row][kc]) = p.u64;
    }
#pragma unroll
    for (int q = 0; q < 4; ++q) {
      int idx = q * 256 + tid;
      int row = idx >> 3;
      int kc = (idx & 7) << 3;
      *reinterpret_cast<u16x8*>(&Bs[row][kc]) =
          *reinterpret_cast<const u16x8*>(&W1T[(size_t)(n0 + row) * H + k0 + kc]);
    }
    __syncthreads();
#pragma unroll
    for (int ks = 0; ks < 2; ++ks) {
      const int kofs = ks * 32 + 8 * hi;
      bf16x8 a[4], bb[4];
#pragma unroll
      for (int i = 0; i < 4; ++i)
        a[i] = *reinterpret_cast<const bf16x8*>(&As[wm * 64 + i * 16 + li][kofs]);
#pragma unroll
      for (int i = 0; i < 4; ++i)
        bb[i] = *reinterpret_cast<const bf16x8*>(&Bs[wn * 64 + i * 16 + li][kofs]);
#pragma unroll
      for (int mi = 0; mi < 4; ++mi)
#pragma unroll
        for (int ni = 0; ni < 4; ++ni)
          acc[mi][ni] = __builtin_amdgcn_mfma_f32_16x16x32_bf16(a[mi], bb[ni], acc[mi][ni], 0, 0, 0);
    }
  }
  const int b = m0 >> 11;
  float bias[4], vv[4];
#pragma unroll
  for (int ni = 0; ni < 4; ++ni) {
    int u = n0 + wn * 64 + ni * 16 + li;
    bias[ni] = b1[u] + projq[b * UNITS + u];
    vv[ni] = V[u];
  }
#pragma unroll
  for (int mi = 0; mi < 4; ++mi) {
#pragma unroll
    for (int r = 0; r < 4; ++r) {
      float s = 0.f;
#pragma unroll
      for (int ni = 0; ni < 4; ++ni) {
        float x = acc[mi][ni][r] + bias[ni];
        float e = __expf(2.f * x);
        s += (1.f - 2.f / (e + 1.f)) * vv[ni];
      }
      s += __shfl_xor(s, 1);
      s += __shfl_xor(s, 2);
      s += __shfl_xor(s, 4);
      s += __shfl_xor(s, 8);
      if (li == 0) atomicAdd(&scores[m0 + wm * 64 + mi * 16 + hi * 4 + r], s);
    }
  }
}

// ---- softmax over S per batch; bv cancels ----
__global__ void k_softmax(const float* __restrict__ scores, float* __restrict__ wts) {
  __shared__ float red[8];
  int b = blockIdx.x;
  int t = threadIdx.x;
  float v[8];
  float mx = -3.4e38f;
#pragma unroll
  for (int i = 0; i < 8; ++i) {
    v[i] = scores[b * SEQ + i * 256 + t];
    mx = fmaxf(mx, v[i]);
  }
#pragma unroll
  for (int o = 1; o < 64; o <<= 1) mx = fmaxf(mx, __shfl_xor(mx, o));
  if ((t & 63) == 0) red[t >> 6] = mx;
  __syncthreads();
  mx = fmaxf(fmaxf(red[0], red[1]), fmaxf(red[2], red[3]));
  float sum = 0.f;
#pragma unroll
  for (int i = 0; i < 8; ++i) { v[i] = __expf(v[i] - mx); sum += v[i]; }
#pragma unroll
  for (int o = 1; o < 64; o <<= 1) sum += __shfl_xor(sum, o);
  if ((t & 63) == 0) red[4 + (t >> 6)] = sum;
  __syncthreads();
  float inv = 1.f / (red[4] + red[5] + red[6] + red[7]);
#pragma unroll
  for (int i = 0; i < 8; ++i) wts[b * SEQ + i * 256 + t] = v[i] * inv;
}

// ---- context from bf16 values: ctx[b][h] = sum_s w[b][s]*v[b][s][h] ----
__global__ void k_context_bf(const unsigned short* __restrict__ Vb,
                             const float* __restrict__ wts, float* __restrict__ ctx) {
  int b = blockIdx.x, sc = blockIdx.y;
  int h4 = threadIdx.x * 4;
  const unsigned short* vb = Vb + (size_t)b * SEQ * H;
  float a0 = 0, a1 = 0, a2 = 0, a3 = 0;
  int s0 = sc * 128;
#pragma unroll 4
  for (int s = s0; s < s0 + 128; ++s) {
    float w = wts[b * SEQ + s];
    ushort4 v = *reinterpret_cast<const ushort4*>(&vb[(size_t)s * H + h4]);
    a0 = fmaf(w, bf2f(v.x), a0);
    a1 = fmaf(w, bf2f(v.y), a1);
    a2 = fmaf(w, bf2f(v.z), a2);
    a3 = fmaf(w, bf2f(v.w), a3);
  }
  atomicAdd(&ctx[b * H + h4 + 0], a0);
  atomicAdd(&ctx[b * H + h4 + 1], a1);
  atomicAdd(&ctx[b * H + h4 + 2], a2);
  atomicAdd(&ctx[b * H + h4 + 3], a3);
}

// ---- fp32 context (fallback path) ----
__global__ void k_context(const float* __restrict__ values, const float* __restrict__ wts,
                          float* __restrict__ ctx) {
  int b = blockIdx.x, hc = blockIdx.y, sc = blockIdx.z;
  int h = hc * 256 + threadIdx.x;
  const float* vb = values + (size_t)b * SEQ * H;
  float acc = 0.f;
  int s0 = sc * 128;
#pragma unroll 4
  for (int s = s0; s < s0 + 128; ++s)
    acc = fmaf(wts[b * SEQ + s], vb[(size_t)s * H + h], acc);
  atomicAdd(&ctx[b * H + h], acc);
}

extern "C" void kernel_launch(void* const* d_in, const int* in_sizes, int n_in,
                              void* d_out, int out_size, void* d_ws, size_t ws_size,
                              hipStream_t stream) {
  (void)in_sizes; (void)n_in; (void)out_size;
  const float* query  = (const float*)d_in[0];
  const float* values = (const float*)d_in[1];
  const float* W1     = (const float*)d_in[2];
  const float* b1     = (const float*)d_in[3];
  const float* W2     = (const float*)d_in[4];
  const float* b2     = (const float*)d_in[5];
  const float* V      = (const float*)d_in[6];
  // d_in[7] = bv: cancels in softmax -> unused.

  float* out = (float*)d_out;
  float* ctx = out;             // [32][1024]
  float* wts = out + BATCH * H; // [32][2048]

  const size_t vb_bytes = (size_t)M_TOT * H * 2;  // 128 MB
  const size_t need = vb_bytes + (2u << 20) + (256u << 10) + (128u << 10);

  if (ws_size >= need) {
    char* ws = (char*)d_ws;
    unsigned short* Vb  = (unsigned short*)ws;
    unsigned short* W1T = (unsigned short*)(ws + vb_bytes);
    float* scores = (float*)(ws + vb_bytes + (2u << 20));
    float* projq  = (float*)(ws + vb_bytes + (2u << 20) + (256u << 10));

    hipMemsetAsync(scores, 0, M_TOT * sizeof(float), stream);
    hipMemsetAsync(ctx, 0, BATCH * H * sizeof(float), stream);

    k_cast<<<(M_TOT * H / 8) / 256, 256, 0, stream>>>(values, Vb);
    k_transpose_w1<<<dim3(32, 32), dim3(32, 8), 0, stream>>>(W1, W1T);
    k_projq<<<dim3(32, 4), 256, 0, stream>>>(query, W2, b2, projq);
    k_score2<<<(M_TOT / BM) * (UNITS / BN), 256, 0, stream>>>(Vb, W1T, b1, projq, V, scores);
    k_softmax<<<BATCH, 256, 0, stream>>>(scores, wts);
    k_context_bf<<<dim3(BATCH, 16), 256, 0, stream>>>(Vb, wts, ctx);
  } else {
    char* ws = (char*)d_ws;
    unsigned short* W1T = (unsigned short*)ws;
    float* scores = (float*)(ws + (2u << 20));
    float* projq  = (float*)(ws + (2u << 20) + (256u << 10));

    hipMemsetAsync(scores, 0, M_TOT * sizeof(float), stream);
    hipMemsetAsync(ctx, 0, BATCH * H * sizeof(float), stream);

    k_transpose_w1<<<dim3(32, 32), dim3(32, 8), 0, stream>>>(W1, W1T);
    k_projq<<<dim3(32, 4), 256, 0, stream>>>(query, W2, b2, projq);
    k_score_f32<<<dim3(UNITS / BN, M_TOT / BM), 256, 0, stream>>>(values, W1T, b1, projq, V, scores);
    k_softmax<<<BATCH, 256, 0, stream>>>(scores, wts);
    k_context<<<dim3(BATCH, H / 256, 16), 256, 0, stream>>>(values, wts, ctx);
  }
}

// Round 5
// 342.971 us; speedup vs baseline: 1.2874x; 1.0385x over previous
//
#include <hip/hip_runtime.h>

#define H 1024
#define UNITS 1024
#define BATCH 32
#define SEQ 2048
#define M_TOT (BATCH * SEQ)  // 65536

typedef __attribute__((ext_vector_type(8))) short bf16x8;
typedef __attribute__((ext_vector_type(8))) unsigned short u16x8;
typedef __attribute__((ext_vector_type(4))) float f32x4;

__device__ __forceinline__ unsigned short f2bf(float f) {
  union { float f; unsigned u; } x; x.f = f;
  unsigned r = x.u + 0x7FFFu + ((x.u >> 16) & 1u);  // RTN-even
  return (unsigned short)(r >> 16);
}
__device__ __forceinline__ float bf2f(unsigned short h) {
  union { unsigned u; float f; } x; x.u = (unsigned)h << 16;
  return x.f;
}

// async global->LDS, 16B per lane; LDS dest = wave-uniform base + lane*16
__device__ __forceinline__ void gll16(const unsigned short* g, unsigned short* l) {
  __builtin_amdgcn_global_load_lds(
      (const __attribute__((address_space(1))) void*)g,
      (__attribute__((address_space(3))) void*)l, 16, 0, 0);
}

// ---- values fp32 -> bf16 (one-shot, BW-bound) ----
__global__ void k_cast(const float* __restrict__ in, unsigned short* __restrict__ out) {
  size_t i = ((size_t)blockIdx.x * 256 + threadIdx.x) * 8;
  float4 v0 = *reinterpret_cast<const float4*>(in + i);
  float4 v1 = *reinterpret_cast<const float4*>(in + i + 4);
  union { unsigned short h[8]; u16x8 v; } p;
  p.h[0] = f2bf(v0.x); p.h[1] = f2bf(v0.y); p.h[2] = f2bf(v0.z); p.h[3] = f2bf(v0.w);
  p.h[4] = f2bf(v1.x); p.h[5] = f2bf(v1.y); p.h[6] = f2bf(v1.z); p.h[7] = f2bf(v1.w);
  *reinterpret_cast<u16x8*>(out + i) = p.v;
}

// ---- W1 [H][U] fp32 -> W1T [U][H] bf16 ----
__global__ void k_transpose_w1(const float* __restrict__ W1, unsigned short* __restrict__ W1T) {
  __shared__ float tile[32][33];
  int bx = blockIdx.x, by = blockIdx.y;
  int tx = threadIdx.x, ty = threadIdx.y;
#pragma unroll
  for (int i = 0; i < 4; ++i)
    tile[ty + i * 8][tx] = W1[(by * 32 + ty + i * 8) * UNITS + bx * 32 + tx];
  __syncthreads();
#pragma unroll
  for (int i = 0; i < 4; ++i)
    W1T[(bx * 32 + ty + i * 8) * H + by * 32 + tx] = f2bf(tile[tx][ty + i * 8]);
}

// ---- projq[b][u] = query[b,:] @ W2[:,u] + b2[u]  (fp32) ----
__global__ void k_projq(const float* __restrict__ query, const float* __restrict__ W2,
                        const float* __restrict__ b2, float* __restrict__ projq) {
  __shared__ float q[H];
  int b = blockIdx.x;
  int u = blockIdx.y * 256 + threadIdx.x;
  for (int i = threadIdx.x; i < H; i += 256) q[i] = query[b * H + i];
  __syncthreads();
  float acc = 0.f;
#pragma unroll 8
  for (int k = 0; k < H; ++k) acc = fmaf(q[k], W2[k * UNITS + u], acc);
  projq[b * UNITS + u] = acc + b2[u];
}

// ============ 256x256 8-phase fused GEMM + tanh + dot(V) -> scores ===========
// T3+T4+T5 template: 512 thr / 8 waves (2M x 4N), BK=64, 128 KB LDS
// [2 dbuf][2 khalf][256 rows][32 k-halves]. 4 phases per K-tile (kh x nh),
// 16 MFMA each. K-tile t+1 staged during t's phases (1 half-stage/phase,
// 2 gll16 ea), counted vmcnt(4) ONLY at phases 0/2 — the newest 4 loads are
// next-tile stages, so current-tile halves are provably landed; never drain
// to 0 in the loop. Stage issued AFTER the barrier: previous occupant's
// ds_reads complete before their consuming MFMAs, which precede that barrier
// -> slot reuse race-free. Half-slot row stride = 64 B -> frag reads spread
// uniformly across bank groups (no swizzle needed). Tail: dummy re-stage of
// tile 15 keeps the vmcnt ledger uniform.
#define BM 256
#define BN 256
#define NT 16  // K-tiles of 64

__global__ __launch_bounds__(512, 2) void k_score3(
    const unsigned short* __restrict__ Vb,   // values bf16 [M_TOT][H]
    const unsigned short* __restrict__ W1T,  // [UNITS][H] bf16
    const float* __restrict__ b1,
    const float* __restrict__ projq,         // [BATCH][UNITS]
    const float* __restrict__ V,
    float* __restrict__ scores)              // [M_TOT], pre-zeroed
{
  __shared__ unsigned short As[2][2][256][32];  // 64 KB
  __shared__ unsigned short Bs[2][2][256][32];  // 64 KB

  const int tid = threadIdx.x;
  const int lane = tid & 63;
  const int wave = tid >> 6;        // 0..7
  const int wm = wave >> 2;         // 0..1 -> rows wm*128..+128
  const int wn = wave & 3;          // 0..3 -> cols wn*64..+64
  const int li = lane & 15, hi = lane >> 4;
  const int hi8 = hi * 8;

  // XCD-bijective swizzle: all 4 N-tiles of an M-tile on one XCD, consecutive.
  const int g = blockIdx.x;
  const int xcd = g & 7;
  const int local = g >> 3;          // 0..127
  const int n_t = local & 3;
  const int m_t = xcd + ((local >> 2) << 3);  // 0..255, bijective
  const int m0 = m_t * BM;
  const int n0 = n_t * BN;

  // staging geometry: chunk = 16 rows x 64 B; 2 chunks per wave per half-stage
  const int srow = wave * 32 + (lane >> 2);     // global row offset within tile
  const int scol = (lane & 3) << 3;             // k-halves within the 32-half slot

  auto STAGE_A = [&](int bf, int kt, int kh) {
    const unsigned short* src =
        Vb + (size_t)(m0 + srow) * H + kt * 64 + kh * 32 + scol;
    unsigned short* dst = &As[bf][kh][wave * 32][0];
    gll16(src, dst);
    gll16(src + (size_t)16 * H, dst + 16 * 32);
  };
  auto STAGE_B = [&](int bf, int kt, int kh) {
    const unsigned short* src =
        W1T + (size_t)(n0 + srow) * H + kt * 64 + kh * 32 + scol;
    unsigned short* dst = &Bs[bf][kh][wave * 32][0];
    gll16(src, dst);
    gll16(src + (size_t)16 * H, dst + 16 * 32);
  };

  f32x4 acc[8][4] = {};

  // prologue: K-tile 0 -> buf 0, issue order A0,B0,A1,B1 (ledger depends on it)
  STAGE_A(0, 0, 0);
  STAGE_B(0, 0, 0);
  STAGE_A(0, 0, 1);
  STAGE_B(0, 0, 1);

#pragma unroll 2
  for (int c = 0; c < NT; ++c) {
    const int buf = c & 1, nbuf = buf ^ 1;
    const int cn = (c < NT - 1) ? c + 1 : NT - 1;  // tail: dummy re-stage

    bf16x8 a[8], b0, b1v;

    // ---- phase 0: kh=0, nh=0 ----
    asm volatile("s_waitcnt vmcnt(4)" ::: "memory");  // A0(c),B0(c) landed
    __builtin_amdgcn_s_barrier();
    STAGE_A(nbuf, cn, 0);
#pragma unroll
    for (int i = 0; i < 8; ++i)
      a[i] = *reinterpret_cast<const bf16x8*>(&As[buf][0][wm * 128 + i * 16 + li][hi8]);
    b0  = *reinterpret_cast<const bf16x8*>(&Bs[buf][0][wn * 64 + 0 * 16 + li][hi8]);
    b1v = *reinterpret_cast<const bf16x8*>(&Bs[buf][0][wn * 64 + 1 * 16 + li][hi8]);
    __builtin_amdgcn_s_setprio(1);
#pragma unroll
    for (int i = 0; i < 8; ++i) {
      acc[i][0] = __builtin_amdgcn_mfma_f32_16x16x32_bf16(a[i], b0, acc[i][0], 0, 0, 0);
      acc[i][1] = __builtin_amdgcn_mfma_f32_16x16x32_bf16(a[i], b1v, acc[i][1], 0, 0, 0);
    }
    __builtin_amdgcn_s_setprio(0);

    // ---- phase 1: kh=0, nh=1 ----
    STAGE_B(nbuf, cn, 0);
    b0  = *reinterpret_cast<const bf16x8*>(&Bs[buf][0][wn * 64 + 2 * 16 + li][hi8]);
    b1v = *reinterpret_cast<const bf16x8*>(&Bs[buf][0][wn * 64 + 3 * 16 + li][hi8]);
    __builtin_amdgcn_s_setprio(1);
#pragma unroll
    for (int i = 0; i < 8; ++i) {
      acc[i][2] = __builtin_amdgcn_mfma_f32_16x16x32_bf16(a[i], b0, acc[i][2], 0, 0, 0);
      acc[i][3] = __builtin_amdgcn_mfma_f32_16x16x32_bf16(a[i], b1v, acc[i][3], 0, 0, 0);
    }
    __builtin_amdgcn_s_setprio(0);

    // ---- phase 2: kh=1, nh=0 ----
    asm volatile("s_waitcnt vmcnt(4)" ::: "memory");  // A1(c),B1(c) landed
    __builtin_amdgcn_s_barrier();
    STAGE_A(nbuf, cn, 1);
#pragma unroll
    for (int i = 0; i < 8; ++i)
      a[i] = *reinterpret_cast<const bf16x8*>(&As[buf][1][wm * 128 + i * 16 + li][hi8]);
    b0  = *reinterpret_cast<const bf16x8*>(&Bs[buf][1][wn * 64 + 0 * 16 + li][hi8]);
    b1v = *reinterpret_cast<const bf16x8*>(&Bs[buf][1][wn * 64 + 1 * 16 + li][hi8]);
    __builtin_amdgcn_s_setprio(1);
#pragma unroll
    for (int i = 0; i < 8; ++i) {
      acc[i][0] = __builtin_amdgcn_mfma_f32_16x16x32_bf16(a[i], b0, acc[i][0], 0, 0, 0);
      acc[i][1] = __builtin_amdgcn_mfma_f32_16x16x32_bf16(a[i], b1v, acc[i][1], 0, 0, 0);
    }
    __builtin_amdgcn_s_setprio(0);

    // ---- phase 3: kh=1, nh=1 ----
    STAGE_B(nbuf, cn, 1);
    b0  = *reinterpret_cast<const bf16x8*>(&Bs[buf][1][wn * 64 + 2 * 16 + li][hi8]);
    b1v = *reinterpret_cast<const bf16x8*>(&Bs[buf][1][wn * 64 + 3 * 16 + li][hi8]);
    __builtin_amdgcn_s_setprio(1);
#pragma unroll
    for (int i = 0; i < 8; ++i) {
      acc[i][2] = __builtin_amdgcn_mfma_f32_16x16x32_bf16(a[i], b0, acc[i][2], 0, 0, 0);
      acc[i][3] = __builtin_amdgcn_mfma_f32_16x16x32_bf16(a[i], b1v, acc[i][3], 0, 0, 0);
    }
    __builtin_amdgcn_s_setprio(0);
  }

  // epilogue: partial score[row] = sum_u tanh(acc + b1[u] + projq[b][u]) * V[u]
  const int b = m0 >> 11;  // BM=256 divides SEQ=2048 -> batch uniform per block
  float bias[4], vv[4];
#pragma unroll
  for (int j = 0; j < 4; ++j) {
    int u = n0 + wn * 64 + j * 16 + li;
    bias[j] = b1[u] + projq[b * UNITS + u];
    vv[j] = V[u];
  }
#pragma unroll
  for (int mi = 0; mi < 8; ++mi) {
#pragma unroll
    for (int r = 0; r < 4; ++r) {
      float s = 0.f;
#pragma unroll
      for (int j = 0; j < 4; ++j) {
        float x = acc[mi][j][r] + bias[j];
        float e = __expf(2.f * x);       // tanh(x) = 1 - 2/(e^(2x)+1)
        s += (1.f - 2.f / (e + 1.f)) * vv[j];
      }
      s += __shfl_xor(s, 1);
      s += __shfl_xor(s, 2);
      s += __shfl_xor(s, 4);
      s += __shfl_xor(s, 8);
      if (li == 0) {
        int row = m0 + wm * 128 + mi * 16 + hi * 4 + r;
        atomicAdd(&scores[row], s);
      }
    }
  }
}

// ---- fallback fp32-A score kernel (used only if ws too small) ----
#define FBM 128
#define FBN 128
#define FBK 64
#define LDK 72
__global__ __launch_bounds__(256) void k_score_f32(
    const float* __restrict__ values, const unsigned short* __restrict__ W1T,
    const float* __restrict__ b1, const float* __restrict__ projq,
    const float* __restrict__ V, float* __restrict__ scores)
{
  __shared__ unsigned short Asf[FBM][LDK];
  __shared__ unsigned short Bsf[FBN][LDK];
  const int tid = threadIdx.x;
  const int lane = tid & 63;
  const int wave = tid >> 6;
  const int wm = wave >> 1, wn = wave & 1;
  const int li = lane & 15, hi = lane >> 4;
  const int n0 = blockIdx.x * FBN;
  const int m0 = blockIdx.y * FBM;
  f32x4 acc[4][4] = {};
  for (int k0 = 0; k0 < H; k0 += FBK) {
    __syncthreads();
#pragma unroll
    for (int q = 0; q < 8; ++q) {
      int idx = q * 256 + tid;
      int row = idx >> 4;
      int kc = (idx & 15) << 2;
      float4 v = *reinterpret_cast<const float4*>(&values[(size_t)(m0 + row) * H + k0 + kc]);
      union { unsigned short h[4]; unsigned long long u64; } p;
      p.h[0] = f2bf(v.x); p.h[1] = f2bf(v.y); p.h[2] = f2bf(v.z); p.h[3] = f2bf(v.w);
      *reinterpret_cast<unsigned long long*>(&Asf[row][kc]) = p.u64;
    }
#pragma unroll
    for (int q = 0; q < 4; ++q) {
      int idx = q * 256 + tid;
      int row = idx >> 3;
      int kc = (idx & 7) << 3;
      *reinterpret_cast<u16x8*>(&Bsf[row][kc]) =
          *reinterpret_cast<const u16x8*>(&W1T[(size_t)(n0 + row) * H + k0 + kc]);
    }
    __syncthreads();
#pragma unroll
    for (int ks = 0; ks < 2; ++ks) {
      const int kofs = ks * 32 + 8 * hi;
      bf16x8 a[4], bb[4];
#pragma unroll
      for (int i = 0; i < 4; ++i)
        a[i] = *reinterpret_cast<const bf16x8*>(&Asf[wm * 64 + i * 16 + li][kofs]);
#pragma unroll
      for (int i = 0; i < 4; ++i)
        bb[i] = *reinterpret_cast<const bf16x8*>(&Bsf[wn * 64 + i * 16 + li][kofs]);
#pragma unroll
      for (int mi = 0; mi < 4; ++mi)
#pragma unroll
        for (int ni = 0; ni < 4; ++ni)
          acc[mi][ni] = __builtin_amdgcn_mfma_f32_16x16x32_bf16(a[mi], bb[ni], acc[mi][ni], 0, 0, 0);
    }
  }
  const int b = m0 >> 11;
  float bias[4], vv[4];
#pragma unroll
  for (int ni = 0; ni < 4; ++ni) {
    int u = n0 + wn * 64 + ni * 16 + li;
    bias[ni] = b1[u] + projq[b * UNITS + u];
    vv[ni] = V[u];
  }
#pragma unroll
  for (int mi = 0; mi < 4; ++mi) {
#pragma unroll
    for (int r = 0; r < 4; ++r) {
      float s = 0.f;
#pragma unroll
      for (int ni = 0; ni < 4; ++ni) {
        float x = acc[mi][ni][r] + bias[ni];
        float e = __expf(2.f * x);
        s += (1.f - 2.f / (e + 1.f)) * vv[ni];
      }
      s += __shfl_xor(s, 1);
      s += __shfl_xor(s, 2);
      s += __shfl_xor(s, 4);
      s += __shfl_xor(s, 8);
      if (li == 0) atomicAdd(&scores[m0 + wm * 64 + mi * 16 + hi * 4 + r], s);
    }
  }
}

// ---- softmax over S per batch; bv cancels ----
__global__ void k_softmax(const float* __restrict__ scores, float* __restrict__ wts) {
  __shared__ float red[8];
  int b = blockIdx.x;
  int t = threadIdx.x;
  float v[8];
  float mx = -3.4e38f;
#pragma unroll
  for (int i = 0; i < 8; ++i) {
    v[i] = scores[b * SEQ + i * 256 + t];
    mx = fmaxf(mx, v[i]);
  }
#pragma unroll
  for (int o = 1; o < 64; o <<= 1) mx = fmaxf(mx, __shfl_xor(mx, o));
  if ((t & 63) == 0) red[t >> 6] = mx;
  __syncthreads();
  mx = fmaxf(fmaxf(red[0], red[1]), fmaxf(red[2], red[3]));
  float sum = 0.f;
#pragma unroll
  for (int i = 0; i < 8; ++i) { v[i] = __expf(v[i] - mx); sum += v[i]; }
#pragma unroll
  for (int o = 1; o < 64; o <<= 1) sum += __shfl_xor(sum, o);
  if ((t & 63) == 0) red[4 + (t >> 6)] = sum;
  __syncthreads();
  float inv = 1.f / (red[4] + red[5] + red[6] + red[7]);
#pragma unroll
  for (int i = 0; i < 8; ++i) wts[b * SEQ + i * 256 + t] = v[i] * inv;
}

// ---- context from bf16 values: ctx[b][h] = sum_s w[b][s]*v[b][s][h] ----
__global__ void k_context_bf(const unsigned short* __restrict__ Vb,
                             const float* __restrict__ wts, float* __restrict__ ctx) {
  int b = blockIdx.x, sc = blockIdx.y;
  int h4 = threadIdx.x * 4;
  const unsigned short* vb = Vb + (size_t)b * SEQ * H;
  float a0 = 0, a1 = 0, a2 = 0, a3 = 0;
  int s0 = sc * 128;
#pragma unroll 4
  for (int s = s0; s < s0 + 128; ++s) {
    float w = wts[b * SEQ + s];
    ushort4 v = *reinterpret_cast<const ushort4*>(&vb[(size_t)s * H + h4]);
    a0 = fmaf(w, bf2f(v.x), a0);
    a1 = fmaf(w, bf2f(v.y), a1);
    a2 = fmaf(w, bf2f(v.z), a2);
    a3 = fmaf(w, bf2f(v.w), a3);
  }
  atomicAdd(&ctx[b * H + h4 + 0], a0);
  atomicAdd(&ctx[b * H + h4 + 1], a1);
  atomicAdd(&ctx[b * H + h4 + 2], a2);
  atomicAdd(&ctx[b * H + h4 + 3], a3);
}

// ---- fp32 context (fallback path) ----
__global__ void k_context(const float* __restrict__ values, const float* __restrict__ wts,
                          float* __restrict__ ctx) {
  int b = blockIdx.x, hc = blockIdx.y, sc = blockIdx.z;
  int h = hc * 256 + threadIdx.x;
  const float* vb = values + (size_t)b * SEQ * H;
  float acc = 0.f;
  int s0 = sc * 128;
#pragma unroll 4
  for (int s = s0; s < s0 + 128; ++s)
    acc = fmaf(wts[b * SEQ + s], vb[(size_t)s * H + h], acc);
  atomicAdd(&ctx[b * H + h], acc);
}

extern "C" void kernel_launch(void* const* d_in, const int* in_sizes, int n_in,
                              void* d_out, int out_size, void* d_ws, size_t ws_size,
                              hipStream_t stream) {
  (void)in_sizes; (void)n_in; (void)out_size;
  const float* query  = (const float*)d_in[0];
  const float* values = (const float*)d_in[1];
  const float* W1     = (const float*)d_in[2];
  const float* b1     = (const float*)d_in[3];
  const float* W2     = (const float*)d_in[4];
  const float* b2     = (const float*)d_in[5];
  const float* V      = (const float*)d_in[6];
  // d_in[7] = bv: cancels in softmax -> unused.

  float* out = (float*)d_out;
  float* ctx = out;             // [32][1024]
  float* wts = out + BATCH * H; // [32][2048]

  const size_t vb_bytes = (size_t)M_TOT * H * 2;  // 128 MB
  const size_t need = vb_bytes + (2u << 20) + (256u << 10) + (128u << 10);

  if (ws_size >= need) {
    char* ws = (char*)d_ws;
    unsigned short* Vb  = (unsigned short*)ws;
    unsigned short* W1T = (unsigned short*)(ws + vb_bytes);
    float* scores = (float*)(ws + vb_bytes + (2u << 20));
    float* projq  = (float*)(ws + vb_bytes + (2u << 20) + (256u << 10));

    hipMemsetAsync(scores, 0, M_TOT * sizeof(float), stream);
    hipMemsetAsync(ctx, 0, BATCH * H * sizeof(float), stream);

    k_cast<<<(M_TOT * H / 8) / 256, 256, 0, stream>>>(values, Vb);
    k_transpose_w1<<<dim3(32, 32), dim3(32, 8), 0, stream>>>(W1, W1T);
    k_projq<<<dim3(32, 4), 256, 0, stream>>>(query, W2, b2, projq);
    k_score3<<<(M_TOT / BM) * (UNITS / BN), 512, 0, stream>>>(Vb, W1T, b1, projq, V, scores);
    k_softmax<<<BATCH, 256, 0, stream>>>(scores, wts);
    k_context_bf<<<dim3(BATCH, 16), 256, 0, stream>>>(Vb, wts, ctx);
  } else {
    char* ws = (char*)d_ws;
    unsigned short* W1T = (unsigned short*)ws;
    float* scores = (float*)(ws + (2u << 20));
    float* projq  = (float*)(ws + (2u << 20) + (256u << 10));

    hipMemsetAsync(scores, 0, M_TOT * sizeof(float), stream);
    hipMemsetAsync(ctx, 0, BATCH * H * sizeof(float), stream);

    k_transpose_w1<<<dim3(32, 32), dim3(32, 8), 0, stream>>>(W1, W1T);
    k_projq<<<dim3(32, 4), 256, 0, stream>>>(query, W2, b2, projq);
    k_score_f32<<<dim3(UNITS / FBN, M_TOT / FBM), 256, 0, stream>>>(values, W1T, b1, projq, V, scores);
    k_softmax<<<BATCH, 256, 0, stream>>>(scores, wts);
    k_context<<<dim3(BATCH, H / 256, 16), 256, 0, stream>>>(values, wts, ctx);
  }
}